// Round 1
// baseline (63.013 us; speedup 1.0000x reference)
//
#include <hip/hip_runtime.h>
#include <hip/hip_fp16.h>

// TensorFusion: out = tanh(tanh(tanh(fusion@W1+b1)@W2+b2)@W3+b3)
// fusion[b,(i,j,k)] = a_h[b,i]*v_h[b,j]*t_h[b,k], a_h=[1,a], etc., 65^3 = 274625 cols.
//
// Decomposition: K-dim splits into 4291 segments of K=64 (+1 constant row):
//   s<4096:        (i',j',k'>=1): scale=a[i]*v[j], inner=l, rowbase=(i+1)*4225+(j+1)*65+1, stride 1
//   4096..4159:    (i',j'>=1,k=0): scale=a[i],     inner=v, rowbase=(i+1)*4225+65,        stride 65
//   4160..4223:    (i'>=1,0,k'):   scale=a[i],     inner=l, rowbase=(i+1)*4225+1,         stride 1
//   4224..4287:    (0,j'>=1,k'):   scale=v[j],     inner=l, rowbase=(j+1)*65+1,           stride 1
//   4288:          (i',0,0):       scale=1,        inner=a, rowbase=4225,                 stride 4225
//   4289:          (0,j',0):       scale=1,        inner=v, rowbase=65,                   stride 65
//   4290:          (0,0,k'):       scale=1,        inner=l, rowbase=1,                    stride 1
//   row 0 (1*1*1*W1[0,:]) folded into tail bias.
// A[b, t] = scale[b]*inner[b,t]  -> generated in-register, f16 MFMA, fp32 accum.
// Grid=256 blocks (1/CU), BM=512 (W1 read exactly ONCE = 70.3MB, the roofline),
// split-K f16 partials [256][512][64] reduced in tail kernel fused with the MLP.

typedef _Float16 f16;
typedef f16 f16x8 __attribute__((ext_vector_type(8)));
typedef f16 f16x2 __attribute__((ext_vector_type(2)));
typedef float f32x4 __attribute__((ext_vector_type(4)));

#define WS_AT      0
#define WS_VT      131072
#define WS_A16     262144
#define WS_V16     327680
#define WS_L16     393216
#define WS_PART    458752   // f16 [256][512][64] = 16777216 B; total ws = 17235968 B

// ---------------- prep: transposes + f16 casts ----------------
__global__ __launch_bounds__(256) void prep_kernel(
    const float* __restrict__ l, const float* __restrict__ a, const float* __restrict__ v,
    float* __restrict__ aT, float* __restrict__ vT,
    f16* __restrict__ a16, f16* __restrict__ v16, f16* __restrict__ l16)
{
  int g = blockIdx.x * 256 + threadIdx.x;   // 5*32768 items
  int which = g >> 15;
  int idx = g & 32767;
  switch (which) {
    case 0: aT[idx] = a[((idx & 511) << 6) + (idx >> 9)]; break;  // aT[c][r]=a[r][c]
    case 1: vT[idx] = v[((idx & 511) << 6) + (idx >> 9)]; break;
    case 2: a16[idx] = (f16)a[idx]; break;
    case 3: v16[idx] = (f16)v[idx]; break;
    case 4: l16[idx] = (f16)l[idx]; break;
  }
}

__device__ __forceinline__ void seg_decode(int s, int& ia, int& iv, int& isel,
                                           int& rowbase, int& rowstride) {
  if (s < 4096)      { int i = s >> 6, j = s & 63; ia = i; iv = j; isel = 0;
                       rowbase = (i+1)*4225 + (j+1)*65 + 1; rowstride = 1; }
  else if (s < 4160) { int i = s - 4096; ia = i; iv = -1; isel = 2;
                       rowbase = (i+1)*4225 + 65; rowstride = 65; }
  else if (s < 4224) { int i = s - 4160; ia = i; iv = -1; isel = 0;
                       rowbase = (i+1)*4225 + 1; rowstride = 1; }
  else if (s < 4288) { int j = s - 4224; ia = -1; iv = j; isel = 0;
                       rowbase = (j+1)*65 + 1; rowstride = 1; }
  else if (s == 4288){ ia = -1; iv = -1; isel = 1; rowbase = 4225; rowstride = 4225; }
  else if (s == 4289){ ia = -1; iv = -1; isel = 2; rowbase = 65;   rowstride = 65; }
  else               { ia = -1; iv = -1; isel = 0; rowbase = 1;    rowstride = 1; }
}

// ---------------- stage 1: the big implicit GEMM ----------------
__global__ __launch_bounds__(512, 2) void fusion_gemm(
    const float* __restrict__ W1,
    const float* __restrict__ aT, const float* __restrict__ vT,
    const f16* __restrict__ a16, const f16* __restrict__ v16, const f16* __restrict__ l16,
    f16* __restrict__ partials)
{
  __shared__ f16 l_lds[512 * 64];      // [b][k] f16, 16B chunks XOR-swizzled by (b&7)
  __shared__ f16 btile[2][64 * 64];    // Bt[n][k] f16 transposed W1 tile, same swizzle
  __shared__ f16 pl[2][512];           // per-row scale

  const int tid  = threadIdx.x;
  const int bid  = blockIdx.x;
  const int lane = tid & 63;
  const int wave = tid >> 6;
  const int l15  = lane & 15;
  const int l4   = lane >> 4;

  // stage l into LDS (swizzled), fully coalesced 16B chunks
  #pragma unroll
  for (int it = 0; it < 8; ++it) {
    int idx = (it << 9) + tid;          // chunk id 0..4095
    int row = idx >> 3, ch = idx & 7;
    f16x8 val = *(const f16x8*)(l16 + (idx << 3));
    *(f16x8*)&l_lds[(row << 6) + ((ch ^ (row & 7)) << 3)] = val;
  }

  const int s0   = bid * 16 + min(bid, 195);       // 4291 segs over 256 blocks
  const int nseg = 16 + (bid < 195 ? 1 : 0);

  f32x4 acc[4][4] = {};                 // 64 VGPRs: 4 M-tiles x 4 N-tiles of 16x16

  const int n_st = tid & 63;            // staging: col
  const int g_st = tid >> 6;            // staging: k-group (8 rows)

  float wv[8]; float spa, spv;

  { // prologue: loads for segment s0
    int ia, iv, isel, rb, rs;
    seg_decode(s0, ia, iv, isel, rb, rs);
    const float* src = W1 + (long)(rb + g_st * 8 * rs) * 64 + n_st;
    #pragma unroll
    for (int r = 0; r < 8; ++r) wv[r] = src[(long)r * rs * 64];
    spa = (ia >= 0) ? aT[(ia << 9) + tid] : 1.0f;
    spv = (iv >= 0) ? vT[(iv << 9) + tid] : 1.0f;
  }

  for (int ss = 0; ss < nseg; ++ss) {
    const int buf = ss & 1;
    { // cvt + LDS-write staged segment ss (compiler inserts vmcnt wait here)
      f16x8 c;
      #pragma unroll
      for (int r = 0; r < 8; ++r) c[r] = (f16)wv[r];
      *(f16x8*)&btile[buf][(n_st << 6) + ((g_st ^ (n_st & 7)) << 3)] = c;
      pl[buf][tid] = (f16)(spa * spv);
    }
    if (ss + 1 < nseg) { // issue next-segment loads; stay in flight across the MFMA phase
      int ia, iv, isel, rb, rs;
      seg_decode(s0 + ss + 1, ia, iv, isel, rb, rs);
      const float* src = W1 + (long)(rb + g_st * 8 * rs) * 64 + n_st;
      #pragma unroll
      for (int r = 0; r < 8; ++r) wv[r] = src[(long)r * rs * 64];
      spa = (ia >= 0) ? aT[(ia << 9) + tid] : 1.0f;
      spv = (iv >= 0) ? vT[(iv << 9) + tid] : 1.0f;
    }
    __syncthreads();
    { // compute on buf
      int ia, iv, isel, rb, rs;
      seg_decode(s0 + ss, ia, iv, isel, rb, rs);
      const f16* gptr = (isel == 1) ? a16 : v16;
      #pragma unroll
      for (int ks = 0; ks < 2; ++ks) {
        f16x8 bf[4], af[4];
        #pragma unroll
        for (int nt = 0; nt < 4; ++nt) {
          int n = (nt << 4) + l15;
          bf[nt] = *(const f16x8*)&btile[buf][(n << 6) + ((((ks << 2) + l4) ^ (n & 7)) << 3)];
        }
        #pragma unroll
        for (int mt = 0; mt < 4; ++mt) {
          int b = (wave << 6) + (mt << 4) + l15;
          f16 p = pl[buf][b];
          f16x8 lv;
          if (isel == 0) {
            lv = *(const f16x8*)&l_lds[(b << 6) + ((((ks << 2) + l4) ^ (b & 7)) << 3)];
          } else {
            lv = *(const f16x8*)(gptr + (b << 6) + (ks << 5) + (l4 << 3));
          }
          f16x2 pp = { p, p };
          f16x2* lvp = (f16x2*)&lv;
          f16x2* afp = (f16x2*)&af[mt];
          afp[0] = lvp[0] * pp; afp[1] = lvp[1] * pp;
          afp[2] = lvp[2] * pp; afp[3] = lvp[3] * pp;
        }
        #pragma unroll
        for (int mt = 0; mt < 4; ++mt)
          #pragma unroll
          for (int nt = 0; nt < 4; ++nt)
            acc[mt][nt] = __builtin_amdgcn_mfma_f32_16x16x32_f16(af[mt], bf[nt], acc[mt][nt], 0, 0, 0);
      }
    }
  }

  // epilogue: f16 split-K partials. C layout: col=lane&15, row=(lane>>4)*4+reg (m89).
  #pragma unroll
  for (int mt = 0; mt < 4; ++mt)
    #pragma unroll
    for (int nt = 0; nt < 4; ++nt)
      #pragma unroll
      for (int r = 0; r < 4; ++r) {
        int row = (wave << 6) + (mt << 4) + (l4 << 2) + r;
        int col = (nt << 4) + l15;
        partials[(((long)bid << 9) + row) * 64 + col] = (f16)acc[mt][nt][r];
      }
}

// ---------------- tail: reduce partials + bias + tanh + 2x 64x64 GEMM ----------------
__global__ __launch_bounds__(256) void tail_kernel(
    const f16* __restrict__ partials, const float* __restrict__ W1, const float* __restrict__ b1,
    const float* __restrict__ W2, const float* __restrict__ b2,
    const float* __restrict__ W3, const float* __restrict__ b3, float* __restrict__ out)
{
  __shared__ float red[4][64];
  __shared__ float hbuf[64];
  __shared__ float h2buf[64];
  const int row = blockIdx.x;          // 0..511
  const int t = threadIdx.x;
  const int n = t & 63;
  const int q = t >> 6;                // 4-way p split

  float s_[4] = {0.f, 0.f, 0.f, 0.f};
  for (int i = 0; i < 64; i += 4) {
    #pragma unroll
    for (int u = 0; u < 4; ++u) {
      int p = ((i + u) << 2) + q;      // p = q + 4*(i+u)
      s_[u] += (float)partials[((((long)p << 9) + row) << 6) + n];
    }
  }
  red[q][n] = s_[0] + s_[1] + s_[2] + s_[3];
  __syncthreads();
  if (t < 64) {
    float h = red[0][n] + red[1][n] + red[2][n] + red[3][n] + b1[n] + W1[n]; // +row-0 term
    hbuf[n] = tanhf(h);
  }
  __syncthreads();
  if (t < 64) {
    float acc = b2[n];
    #pragma unroll 8
    for (int k = 0; k < 64; ++k) acc += hbuf[k] * W2[(k << 6) + n];
    h2buf[n] = tanhf(acc);
  }
  __syncthreads();
  if (t < 64) {
    float acc = b3[n];
    #pragma unroll 8
    for (int k = 0; k < 64; ++k) acc += h2buf[k] * W3[(k << 6) + n];
    out[(row << 6) + n] = tanhf(acc);
  }
}

extern "C" void kernel_launch(void* const* d_in, const int* in_sizes, int n_in,
                              void* d_out, int out_size, void* d_ws, size_t ws_size,
                              hipStream_t stream) {
  const float* l  = (const float*)d_in[0];
  const float* a  = (const float*)d_in[1];
  const float* v  = (const float*)d_in[2];
  const float* W1 = (const float*)d_in[3];
  const float* b1 = (const float*)d_in[4];
  const float* W2 = (const float*)d_in[5];
  const float* b2 = (const float*)d_in[6];
  const float* W3 = (const float*)d_in[7];
  const float* b3 = (const float*)d_in[8];
  float* out = (float*)d_out;

  char* ws = (char*)d_ws;
  float* aT  = (float*)(ws + WS_AT);
  float* vT  = (float*)(ws + WS_VT);
  f16*   a16 = (f16*)(ws + WS_A16);
  f16*   v16 = (f16*)(ws + WS_V16);
  f16*   l16 = (f16*)(ws + WS_L16);
  f16*   partials = (f16*)(ws + WS_PART);

  hipLaunchKernelGGL(prep_kernel, dim3(640), dim3(256), 0, stream,
                     l, a, v, aT, vT, a16, v16, l16);
  hipLaunchKernelGGL(fusion_gemm, dim3(256), dim3(512), 0, stream,
                     W1, aT, vT, a16, v16, l16, partials);
  hipLaunchKernelGGL(tail_kernel, dim3(512), dim3(256), 0, stream,
                     partials, W1, b1, W2, b2, W3, b3, out);
}